// Round 18
// baseline (62.180 us; speedup 1.0000x reference)
//
#include <hip/hip_runtime.h>

typedef __attribute__((ext_vector_type(8))) short  s8v;
typedef __attribute__((ext_vector_type(8))) __bf16 b8v;
typedef __attribute__((ext_vector_type(4))) float  f4v;
typedef __attribute__((ext_vector_type(2))) float  f2v;

#define LDST 36   // f32 rows: 144 B, 16B-aligned
#define TBL_N 960 // basis LUT: u in [-4, 11], step 1/64

// Wave-local LDS fence (r9 post-mortem)
#define WAVE_FENCE() do { asm volatile("s_waitcnt lgkmcnt(0)" ::: "memory"); \
                          __builtin_amdgcn_sched_barrier(0); } while(0)

// d_ws layout:
//   [0, 768)            : 192 floats  LNP
//   [768, 768+47104)    : 23552 bf16  weights W1|W2|W3|W4  (K-permuted)
#define W2_OFF 2560
#define W3_OFF 5120
#define W4_OFF 14336
#define W_TOTAL 23552
#define PREP_TOTAL (192 + W_TOTAL)

__device__ __forceinline__ float frcp_(float x){ return __builtin_amdgcn_rcpf(x); }
__device__ __forceinline__ float rsq_(float x){ return __builtin_amdgcn_rsqf(x); }
__device__ __forceinline__ float silu_(float x){ return x * frcp_(1.0f + __expf(-x)); }

__device__ __forceinline__ s8v b2s(b8v v){ union { b8v b; s8v s; } u; u.b = v; return u.s; }

__device__ __forceinline__ void gl_lds16(const void* g, void* l){
  __builtin_amdgcn_global_load_lds(
      (const __attribute__((address_space(1))) unsigned int*)g,
      (__attribute__((address_space(3))) unsigned int*)l, 16, 0, 0);
}

__device__ __forceinline__ b8v basis8bf_(float u){
  float b = __expf(-u*u);
  float A = __expf(2.0f*u);
  b8v r;
  r[0] = (__bf16)b;
  b *= A * 0.36787944117144233f;   r[1] = (__bf16)b;
  b *= A * 0.049787068367863944f;  r[2] = (__bf16)b;
  b *= A * 0.006737946999085467f;  r[3] = (__bf16)b;
  b *= A * 0.0009118819655545162f; r[4] = (__bf16)b;
  b *= A * 1.2340980408667956e-4f; r[5] = (__bf16)b;
  b *= A * 1.670170079024566e-5f;  r[6] = (__bf16)b;
  b *= A * 2.2603294069810542e-6f; r[7] = (__bf16)b;
  return r;
}

__device__ __forceinline__ s8v blut_(const s8v* TBL, float u){
  float fi = __builtin_fmaf(u, 64.0f, 256.5f);
  fi = fminf(fmaxf(fi, 0.0f), 959.0f);
  return TBL[(int)fi];
}

__global__ void prep_w(const float* __restrict__ ws1, const float* __restrict__ wb1,
                       const float* __restrict__ ws2, const float* __restrict__ wb2,
                       const float* __restrict__ ws3, const float* __restrict__ wb3,
                       const float* __restrict__ ws4, const float* __restrict__ wb4,
                       const float* __restrict__ g1, const float* __restrict__ b1,
                       const float* __restrict__ g2, const float* __restrict__ b2,
                       const float* __restrict__ g3, const float* __restrict__ b3,
                       const float* __restrict__ g4, const float* __restrict__ b4,
                       float* __restrict__ LNP, __bf16* __restrict__ W){
  int idx = blockIdx.x*256 + threadIdx.x;
  if (idx >= PREP_TOTAL) return;
  if (idx < 192){
    float v;
    if      (idx < 16)  v = 1.75f * g1[idx];
    else if (idx < 32)  v = 1.75f * (b1[idx-16] + 2.0f);
    else if (idx < 48)  v = 1.75f * g2[idx-32];
    else if (idx < 64)  v = 1.75f * (b2[idx-48] + 2.0f);
    else if (idx < 96)  v = 1.75f * g3[idx-64];
    else if (idx < 128) v = 1.75f * (b3[idx-96] + 2.0f);
    else if (idx < 160) v = 1.75f * g4[idx-128];
    else                v = 1.75f * (b4[idx-160] + 2.0f);
    LNP[idx] = v;
    return;
  }
  int widx = idx - 192;
  float v;
  if (widx < W3_OFF){
    int base = (widx >= W2_OFF) ? W2_OFF : 0;
    const float* ws = base ? ws2 : ws1;
    const float* wb = base ? wb2 : wb1;
    int r = widx - base; int o = r/160, k = r%160;
    if (k < 128){
      int ks = k>>5, kg = (k>>3)&3, j = k&7;
      int elem = kg*4 + ks;
      v = ws[o*128 + elem*8 + j];
    } else {
      int kk = k-128; int kg = kk>>3, j = kk&7;
      v = (j<4) ? wb[o*16 + kg*4 + j] : 0.0f;
    }
  } else {
    int base = (widx >= W4_OFF) ? W4_OFF : W3_OFF;
    const float* ws = (base == W4_OFF) ? ws4 : ws3;
    const float* wb = (base == W4_OFF) ? wb4 : wb3;
    int r = widx - base; int o = r/288, k = r%288;
    if (k < 256){
      int ks = k>>5, kg = (k>>3)&3, j = k&7;
      int elem = kg*8 + ks;
      v = ws[o*256 + elem*8 + j];
    } else {
      int kk = k-256; int kg = kk>>3, j = kk&7;
      v = wb[o*32 + kg*8 + j];
    }
  }
  W[widx] = (__bf16)v;
}

__global__ __launch_bounds__(256,2)
void swin_kan_mfma(const float* __restrict__ x,
                   const float* __restrict__ pn_g, const float* __restrict__ pn_b,
                   const float* __restrict__ k1_bb, const float* __restrict__ k2_bb,
                   const float* __restrict__ k3_bb, const float* __restrict__ k4_bb,
                   const float* __restrict__ LNP,
                   const __bf16* __restrict__ Wbf,
                   float* __restrict__ out)
{
  __shared__ __attribute__((aligned(16))) float  yw[2][64][LDST];
  __shared__ __attribute__((aligned(16))) float  zA[2][64][LDST];
  __shared__ __attribute__((aligned(16))) float  LNPs[192];
  __shared__ __attribute__((aligned(16))) __bf16 W3s[9216];   // 18432 B, shared
  __shared__ __attribute__((aligned(16))) s8v    TBL[TBL_N];  // 15360 B, shared

  const int t    = threadIdx.x;
  const int bid  = blockIdx.x;
  const int pair = (bid & 7)*256 + (bid >> 3);   // XCD-chunked swizzle (2048 % 8 == 0)
  const int wave = t >> 6;
  const int lane = t & 63;
  const int fn = lane & 15, kg = lane >> 4;

  int bW[2], h0W[2], w0W[2];
  #pragma unroll
  for (int W=0; W<2; W++){
    int wid = pair*2 + W;
    bW[W]  = wid >> 10;
    h0W[W] = ((wid >> 5) & 31) * 8;
    w0W[W] = (wid & 31) * 8;
  }

  float4 rx0[2], rx1[2];   // residuals for both windows

  // ---- phase 1: x load -> yw[W] (both windows); stage LNP; W3; TBL ----
  {
    int ch = t & 31, h = t >> 5;
    #pragma unroll
    for (int W=0; W<2; W++){
      const float* src = x + (((size_t)(bW[W]*32 + ch)*256 + (h0W[W]+h))*256 + w0W[W]);
      rx0[W] = *(const float4*)(src);
      rx1[W] = *(const float4*)(src + 4);
      int p = h*8;
      yw[W][p+0][ch]=rx0[W].x; yw[W][p+1][ch]=rx0[W].y; yw[W][p+2][ch]=rx0[W].z; yw[W][p+3][ch]=rx0[W].w;
      yw[W][p+4][ch]=rx1[W].x; yw[W][p+5][ch]=rx1[W].y; yw[W][p+6][ch]=rx1[W].z; yw[W][p+7][ch]=rx1[W].w;
    }
    if (t < 192) LNPs[t] = LNP[t];
    const char* gsrc  = (const char*)(Wbf + W3_OFF);
    char*       lbase = (char*)W3s;
    for (int c = wave; c < 18; c += 4){
      gl_lds16(gsrc + c*1024 + lane*16, lbase + c*1024);
    }
    #pragma unroll
    for (int i = 0; i < 4; i++){
      int e = t + i*256;
      if (e < TBL_N){
        float u = -4.0f + (float)e * (1.0f/64.0f);
        TBL[e] = b2s(basis8bf_(u));
      }
    }
  }
  WAVE_FENCE();

  // ---- phase 2: in-place pre-LN on yw[W] (wave-local rows), 2 windows ----
  {
    int pos = t >> 2, part = t & 3;
    #pragma unroll
    for (int W=0; W<2; W++){
      f4v a = *(const f4v*)&yw[W][pos][part*8];
      f4v c = *(const f4v*)&yw[W][pos][part*8+4];
      float s1 = a[0]+a[1]+a[2]+a[3]+c[0]+c[1]+c[2]+c[3];
      float s2 = a[0]*a[0]+a[1]*a[1]+a[2]*a[2]+a[3]*a[3]
               + c[0]*c[0]+c[1]*c[1]+c[2]*c[2]+c[3]*c[3];
      s1 += __shfl_xor(s1,1); s2 += __shfl_xor(s2,1);
      s1 += __shfl_xor(s1,2); s2 += __shfl_xor(s2,2);
      float mu  = s1*(1.0f/32.0f);
      float var = s2*(1.0f/32.0f) - mu*mu;
      float rs  = rsq_(var + 1e-5f);
      f4v g0 = *(const f4v*)&pn_g[part*8], g1 = *(const f4v*)&pn_g[part*8+4];
      f4v b0 = *(const f4v*)&pn_b[part*8], b1 = *(const f4v*)&pn_b[part*8+4];
      f4v o0, o1;
      #pragma unroll
      for (int j=0;j<4;j++){ o0[j] = (a[j]-mu)*rs*g0[j] + b0[j]; o1[j] = (c[j]-mu)*rs*g1[j] + b1[j]; }
      *(f4v*)&yw[W][pos][part*8]   = o0;
      *(f4v*)&yw[W][pos][part*8+4] = o1;
    }
  }
  __syncthreads();   // B1

  // ---- phase 3: k1 (waves 0,1) & k2 (waves 2,3), both windows per thread ----
  {
    const bool br2 = (wave >= 2);
    const __bf16* Wp  = Wbf + (br2 ? W2_OFF : 0);
    const float* bbp = br2 ? k2_bb : k1_bb;
    const int gb = br2 ? 32 : 0, b2b = gb + 16;
    s8v wfr[5];
    #pragma unroll
    for (int ks=0;ks<5;ks++) wfr[ks] = *(const s8v*)&Wp[fn*160 + ks*32 + kg*8];
    f4v bias = *(const f4v*)&bbp[kg*4];
    f4v G  = *(const f4v*)&LNPs[gb  + kg*4];
    f4v B2 = *(const f4v*)&LNPs[b2b + kg*4];

    f4v accs[2][4];
    #pragma unroll
    for (int W=0; W<2; W++){
      f2v va[4], vb[4];
      #pragma unroll
      for (int mi=0; mi<4; mi++){
        const int ck = (wave & 1)*4 + mi;
        const int posA = br2 ? (ck*8 + 2*kg) : ((2*kg)*8 + ck);
        const int posB = posA + (br2 ? 1 : 8);
        va[mi] = *(const f2v*)&yw[W][posA][2*fn];
        vb[mi] = *(const f2v*)&yw[W][posB][2*fn];
      }
      float mu4[4], rs4[4];
      #pragma unroll
      for (int mi=0; mi<4; mi++){
        float s1 = va[mi][0]+va[mi][1]+vb[mi][0]+vb[mi][1];
        float s2 = va[mi][0]*va[mi][0]+va[mi][1]*va[mi][1]+vb[mi][0]*vb[mi][0]+vb[mi][1]*vb[mi][1];
        s1 += __shfl_xor(s1,16); s2 += __shfl_xor(s2,16);
        s1 += __shfl_xor(s1,32); s2 += __shfl_xor(s2,32);
        float mu = s1*(1.0f/16.0f);
        mu4[mi] = mu;
        rs4[mi] = rsq_(s2*(1.0f/16.0f) - mu*mu + 1e-5f);
      }
      #pragma unroll
      for (int mi=0; mi<4; mi++){
        float v[4] = { va[mi][0], va[mi][1], vb[mi][0], vb[mi][1] };
        b8v bb = {};
        #pragma unroll
        for (int j=0;j<4;j++) bb[j] = (__bf16)silu_(v[j]);
        f4v acc = bias;
        #pragma unroll
        for (int ks=0;ks<4;ks++){
          float pp = G[ks]*rs4[mi];
          float qq = __builtin_fmaf(-mu4[mi], pp, B2[ks]);
          float u  = __builtin_fmaf(v[ks], pp, qq);
          acc = __builtin_amdgcn_mfma_f32_16x16x32_bf16(wfr[ks], blut_(TBL, u), acc, 0,0,0);
        }
        acc = __builtin_amdgcn_mfma_f32_16x16x32_bf16(wfr[4], b2s(bb), acc, 0,0,0);
        accs[W][mi] = acc;
      }
    }

    if (!br2){
      #pragma unroll
      for (int W=0; W<2; W++){
        #pragma unroll
        for (int mi=0; mi<4; mi++){
          const int ck = (wave & 1)*4 + mi;
          *(f2v*)&zA[W][(2*kg+0)*8 + ck][2*fn] = f2v{accs[W][mi][0], accs[W][mi][1]};
          *(f2v*)&zA[W][(2*kg+1)*8 + ck][2*fn] = f2v{accs[W][mi][2], accs[W][mi][3]};
        }
      }
    }
    __syncthreads();   // B2
    if (br2){
      #pragma unroll
      for (int W=0; W<2; W++){
        #pragma unroll
        for (int mi=0; mi<4; mi++){
          const int ck = (wave & 1)*4 + mi;
          f2v o0 = *(f2v*)&zA[W][ck*8 + 2*kg+0][2*fn];
          f2v o1 = *(f2v*)&zA[W][ck*8 + 2*kg+1][2*fn];
          o0[0] += accs[W][mi][0]; o0[1] += accs[W][mi][1];
          o1[0] += accs[W][mi][2]; o1[1] += accs[W][mi][3];
          *(f2v*)&zA[W][ck*8 + 2*kg+0][2*fn] = o0;
          *(f2v*)&zA[W][ck*8 + 2*kg+1][2*fn] = o1;
        }
      }
    }
  }
  __syncthreads();   // B3

  // ---- phase 4: k3, both windows per thread ----
  {
    const int r = wave*16 + fn;
    f4v Ga = *(const f4v*)&LNPs[64 + kg*8], Gb = *(const f4v*)&LNPs[64 + kg*8 + 4];
    f4v Ba = *(const f4v*)&LNPs[96 + kg*8], Bb = *(const f4v*)&LNPs[96 + kg*8 + 4];
    float G8[8]  = { Ga[0],Ga[1],Ga[2],Ga[3], Gb[0],Gb[1],Gb[2],Gb[3] };
    float B8[8]  = { Ba[0],Ba[1],Ba[2],Ba[3], Bb[0],Bb[1],Bb[2],Bb[3] };
    f4v bias0 = *(const f4v*)&k3_bb[kg*4];
    f4v bias1 = *(const f4v*)&k3_bb[16 + kg*4];

    #pragma unroll
    for (int W=0; W<2; W++){
      f4v v0 = *(const f4v*)&yw[W][r][kg*8];
      f4v v1 = *(const f4v*)&yw[W][r][kg*8+4];
      float v[8] = { v0[0],v0[1],v0[2],v0[3], v1[0],v1[1],v1[2],v1[3] };
      b8v bb;
      #pragma unroll
      for (int ks=0;ks<8;ks++) bb[ks] = (__bf16)silu_(v[ks]);
      float s1=0.f, s2=0.f;
      #pragma unroll
      for (int ks=0;ks<8;ks++){ s1 += v[ks]; s2 += v[ks]*v[ks]; }
      s1 += __shfl_xor(s1,16); s2 += __shfl_xor(s2,16);
      s1 += __shfl_xor(s1,32); s2 += __shfl_xor(s2,32);
      float mu  = s1*(1.0f/32.0f);
      float var = s2*(1.0f/32.0f) - mu*mu;
      float rs  = rsq_(var + 1e-5f);

      f4v acc0 = bias0, acc1 = bias1;
      #pragma unroll
      for (int ks=0;ks<8;ks++){
        float pp = G8[ks]*rs;
        float qq = __builtin_fmaf(-mu, pp, B8[ks]);
        float u  = __builtin_fmaf(v[ks], pp, qq);
        s8v bf = blut_(TBL, u);
        s8v wa = *(const s8v*)&W3s[fn*288      + ks*32 + kg*8];
        s8v wb = *(const s8v*)&W3s[(16+fn)*288 + ks*32 + kg*8];
        acc0 = __builtin_amdgcn_mfma_f32_16x16x32_bf16(wa, bf, acc0, 0,0,0);
        acc1 = __builtin_amdgcn_mfma_f32_16x16x32_bf16(wb, bf, acc1, 0,0,0);
      }
      {
        s8v wa = *(const s8v*)&W3s[fn*288      + 256 + kg*8];
        s8v wb = *(const s8v*)&W3s[(16+fn)*288 + 256 + kg*8];
        acc0 = __builtin_amdgcn_mfma_f32_16x16x32_bf16(wa, b2s(bb), acc0, 0,0,0);
        acc1 = __builtin_amdgcn_mfma_f32_16x16x32_bf16(wb, b2s(bb), acc1, 0,0,0);
      }
      f4v za0 = *(const f4v*)&zA[W][r][kg*4];
      f4v za1 = *(const f4v*)&zA[W][r][16+kg*4];
      *(f4v*)&zA[W][r][kg*4]    = acc0 + za0;
      *(f4v*)&zA[W][r][16+kg*4] = acc1 + za1;
    }
  }
  WAVE_FENCE();

  // ---- phase 5: k4, both windows per thread ----
  {
    const int r = wave*16 + fn;
    f4v Ga = *(const f4v*)&LNPs[128 + kg*8], Gb = *(const f4v*)&LNPs[128 + kg*8 + 4];
    f4v Ba = *(const f4v*)&LNPs[160 + kg*8], Bb = *(const f4v*)&LNPs[160 + kg*8 + 4];
    float G8[8]  = { Ga[0],Ga[1],Ga[2],Ga[3], Gb[0],Gb[1],Gb[2],Gb[3] };
    float B8[8]  = { Ba[0],Ba[1],Ba[2],Ba[3], Bb[0],Bb[1],Bb[2],Bb[3] };
    f4v bias0 = *(const f4v*)&k4_bb[kg*4];
    f4v bias1 = *(const f4v*)&k4_bb[16 + kg*4];

    #pragma unroll
    for (int W=0; W<2; W++){
      f4v v0 = *(const f4v*)&zA[W][r][kg*8];
      f4v v1 = *(const f4v*)&zA[W][r][kg*8+4];
      float v[8] = { v0[0],v0[1],v0[2],v0[3], v1[0],v1[1],v1[2],v1[3] };
      float s1=0.f, s2=0.f;
      #pragma unroll
      for (int ks=0;ks<8;ks++){ s1 += v[ks]; s2 += v[ks]*v[ks]; }
      s1 += __shfl_xor(s1,16); s2 += __shfl_xor(s2,16);
      s1 += __shfl_xor(s1,32); s2 += __shfl_xor(s2,32);
      float mu  = s1*(1.0f/32.0f);
      float var = s2*(1.0f/32.0f) - mu*mu;
      float rs  = rsq_(var + 1e-5f);

      f4v acc0 = bias0, acc1 = bias1;
      b8v bb;
      #pragma unroll
      for (int ks=0;ks<8;ks++){
        float pp = G8[ks]*rs;
        float qq = __builtin_fmaf(-mu, pp, B8[ks]);
        float u  = __builtin_fmaf(v[ks], pp, qq);
        s8v bf = blut_(TBL, u);
        s8v wa = *(const s8v*)&Wbf[W4_OFF + fn*288      + ks*32 + kg*8];
        s8v wb = *(const s8v*)&Wbf[W4_OFF + (16+fn)*288 + ks*32 + kg*8];
        acc0 = __builtin_amdgcn_mfma_f32_16x16x32_bf16(wa, bf, acc0, 0,0,0);
        acc1 = __builtin_amdgcn_mfma_f32_16x16x32_bf16(wb, bf, acc1, 0,0,0);
        bb[ks] = (__bf16)silu_(v[ks]);
      }
      {
        s8v wa = *(const s8v*)&Wbf[W4_OFF + fn*288      + 256 + kg*8];
        s8v wb = *(const s8v*)&Wbf[W4_OFF + (16+fn)*288 + 256 + kg*8];
        acc0 = __builtin_amdgcn_mfma_f32_16x16x32_bf16(wa, b2s(bb), acc0, 0,0,0);
        acc1 = __builtin_amdgcn_mfma_f32_16x16x32_bf16(wb, b2s(bb), acc1, 0,0,0);
      }
      *(f4v*)&yw[W][r][kg*4]    = acc0;
      *(f4v*)&yw[W][r][16+kg*4] = acc1;
    }
  }
  WAVE_FENCE();

  // ---- phase 6: residual from registers + coalesced store, both windows ----
  {
    int ch = t & 31, h = t >> 5;
    int p = h*8;
    #pragma unroll
    for (int W=0; W<2; W++){
      const size_t base = (((size_t)(bW[W]*32 + ch)*256 + (h0W[W]+h))*256 + w0W[W]);
      float4 v0 = { yw[W][p+0][ch]+rx0[W].x, yw[W][p+1][ch]+rx0[W].y,
                    yw[W][p+2][ch]+rx0[W].z, yw[W][p+3][ch]+rx0[W].w };
      float4 v1 = { yw[W][p+4][ch]+rx1[W].x, yw[W][p+5][ch]+rx1[W].y,
                    yw[W][p+6][ch]+rx1[W].z, yw[W][p+7][ch]+rx1[W].w };
      *(float4*)(out + base)     = v0;
      *(float4*)(out + base + 4) = v1;
    }
  }
}

extern "C" void kernel_launch(void* const* d_in, const int* in_sizes, int n_in,
                              void* d_out, int out_size, void* d_ws, size_t ws_size,
                              hipStream_t stream) {
  const float* x      = (const float*)d_in[0];
  const float* pn_g   = (const float*)d_in[1];
  const float* pn_b   = (const float*)d_in[2];
  const float* k1_ln_g= (const float*)d_in[3];
  const float* k1_ln_b= (const float*)d_in[4];
  const float* k1_ws  = (const float*)d_in[5];
  const float* k1_wb  = (const float*)d_in[6];
  const float* k1_bb  = (const float*)d_in[7];
  const float* k2_ln_g= (const float*)d_in[8];
  const float* k2_ln_b= (const float*)d_in[9];
  const float* k2_ws  = (const float*)d_in[10];
  const float* k2_wb  = (const float*)d_in[11];
  const float* k2_bb  = (const float*)d_in[12];
  const float* k3_ln_g= (const float*)d_in[13];
  const float* k3_ln_b= (const float*)d_in[14];
  const float* k3_ws  = (const float*)d_in[15];
  const float* k3_wb  = (const float*)d_in[16];
  const float* k3_bb  = (const float*)d_in[17];
  const float* k4_ln_g= (const float*)d_in[18];
  const float* k4_ln_b= (const float*)d_in[19];
  const float* k4_ws  = (const float*)d_in[20];
  const float* k4_wb  = (const float*)d_in[21];
  const float* k4_bb  = (const float*)d_in[22];
  float* out = (float*)d_out;
  float*  LNP = (float*)d_ws;
  __bf16* Wbf = (__bf16*)((char*)d_ws + 768);

  hipLaunchKernelGGL(prep_w, dim3((PREP_TOTAL+255)/256), dim3(256), 0, stream,
                     k1_ws, k1_wb, k2_ws, k2_wb, k3_ws, k3_wb, k4_ws, k4_wb,
                     k1_ln_g, k1_ln_b, k2_ln_g, k2_ln_b,
                     k3_ln_g, k3_ln_b, k4_ln_g, k4_ln_b,
                     LNP, Wbf);

  hipLaunchKernelGGL(swin_kan_mfma, dim3(2048), dim3(256), 0, stream,
                     x, pn_g, pn_b,
                     k1_bb, k2_bb, k3_bb, k4_bb,
                     LNP, Wbf, out);
}

// Round 19
// 61.351 us; speedup vs baseline: 1.0135x; 1.0135x over previous
//
#include <hip/hip_runtime.h>

typedef __attribute__((ext_vector_type(8))) short  s8v;
typedef __attribute__((ext_vector_type(8))) __bf16 b8v;
typedef __attribute__((ext_vector_type(4))) float  f4v;
typedef __attribute__((ext_vector_type(2))) float  f2v;

#define LDST 36   // f32 rows: 144 B, 16B-aligned
#define TBL_N 960 // basis LUT: u in [-4, 11], step 1/64

// Wave-local LDS fence (r9 post-mortem): drains this wave's DS ops and stops
// compiler/scheduler reordering. Replaces __syncthreads() where only
// intra-wave cross-lane LDS visibility is needed.
#define WAVE_FENCE() do { asm volatile("s_waitcnt lgkmcnt(0)" ::: "memory"); \
                          __builtin_amdgcn_sched_barrier(0); } while(0)

// d_ws layout:
//   [0, 768)            : 192 floats  LNP  (G1[16] B21[16] G2[16] B22[16] G3[32] B23[32] G4[32] B24[32])
//   [768, 768+47104)    : 23552 bf16  weights W1|W2|W3|W4  (K-permuted, see prep_w)
#define W2_OFF 2560
#define W3_OFF 5120
#define W4_OFF 14336
#define W_TOTAL 23552
#define PREP_TOTAL (192 + W_TOTAL)

__device__ __forceinline__ float frcp_(float x){ return __builtin_amdgcn_rcpf(x); }
__device__ __forceinline__ float rsq_(float x){ return __builtin_amdgcn_rsqf(x); }
__device__ __forceinline__ float silu_(float x){ return x * frcp_(1.0f + __expf(-x)); }

__device__ __forceinline__ s8v b2s(b8v v){ union { b8v b; s8v s; } u; u.b = v; return u.s; }

// async global -> LDS, 16B per lane; lds dest is wave-uniform base + lane*16
__device__ __forceinline__ void gl_lds16(const void* g, void* l){
  __builtin_amdgcn_global_load_lds(
      (const __attribute__((address_space(1))) unsigned int*)g,
      (__attribute__((address_space(3))) unsigned int*)l, 16, 0, 0);
}

// bas[g] = exp(-(u-g)^2); recurrence b_{g+1} = b_g * e^{2u} * e^{-(2g+1)}
__device__ __forceinline__ b8v basis8bf_(float u){
  float b = __expf(-u*u);
  float A = __expf(2.0f*u);
  b8v r;
  r[0] = (__bf16)b;
  b *= A * 0.36787944117144233f;   r[1] = (__bf16)b;
  b *= A * 0.049787068367863944f;  r[2] = (__bf16)b;
  b *= A * 0.006737946999085467f;  r[3] = (__bf16)b;
  b *= A * 0.0009118819655545162f; r[4] = (__bf16)b;
  b *= A * 1.2340980408667956e-4f; r[5] = (__bf16)b;
  b *= A * 1.670170079024566e-5f;  r[6] = (__bf16)b;
  b *= A * 2.2603294069810542e-6f; r[7] = (__bf16)b;
  return r;
}

// LDS LUT lookup: idx = clamp(round((u+4)*64), 0, 959)
__device__ __forceinline__ s8v blut_(const s8v* TBL, float u){
  float fi = __builtin_fmaf(u, 64.0f, 256.5f);
  fi = fminf(fmaxf(fi, 0.0f), 959.0f);
  return TBL[(int)fi];
}

__global__ void prep_w(const float* __restrict__ ws1, const float* __restrict__ wb1,
                       const float* __restrict__ ws2, const float* __restrict__ wb2,
                       const float* __restrict__ ws3, const float* __restrict__ wb3,
                       const float* __restrict__ ws4, const float* __restrict__ wb4,
                       const float* __restrict__ g1, const float* __restrict__ b1,
                       const float* __restrict__ g2, const float* __restrict__ b2,
                       const float* __restrict__ g3, const float* __restrict__ b3,
                       const float* __restrict__ g4, const float* __restrict__ b4,
                       float* __restrict__ LNP, __bf16* __restrict__ W){
  int idx = blockIdx.x*256 + threadIdx.x;
  if (idx >= PREP_TOTAL) return;
  if (idx < 192){
    float v;
    if      (idx < 16)  v = 1.75f * g1[idx];
    else if (idx < 32)  v = 1.75f * (b1[idx-16] + 2.0f);
    else if (idx < 48)  v = 1.75f * g2[idx-32];
    else if (idx < 64)  v = 1.75f * (b2[idx-48] + 2.0f);
    else if (idx < 96)  v = 1.75f * g3[idx-64];
    else if (idx < 128) v = 1.75f * (b3[idx-96] + 2.0f);
    else if (idx < 160) v = 1.75f * g4[idx-128];
    else                v = 1.75f * (b4[idx-160] + 2.0f);
    LNP[idx] = v;
    return;
  }
  int widx = idx - 192;
  float v;
  if (widx < W3_OFF){
    int base = (widx >= W2_OFF) ? W2_OFF : 0;
    const float* ws = base ? ws2 : ws1;
    const float* wb = base ? wb2 : wb1;
    int r = widx - base; int o = r/160, k = r%160;
    if (k < 128){
      int ks = k>>5, kg = (k>>3)&3, j = k&7;
      int elem = kg*4 + ks;
      v = ws[o*128 + elem*8 + j];
    } else {
      int kk = k-128; int kg = kk>>3, j = kk&7;
      v = (j<4) ? wb[o*16 + kg*4 + j] : 0.0f;
    }
  } else {
    int base = (widx >= W4_OFF) ? W4_OFF : W3_OFF;
    const float* ws = (base == W4_OFF) ? ws4 : ws3;
    const float* wb = (base == W4_OFF) ? wb4 : wb3;
    int r = widx - base; int o = r/288, k = r%288;
    if (k < 256){
      int ks = k>>5, kg = (k>>3)&3, j = k&7;
      int elem = kg*8 + ks;
      v = ws[o*256 + elem*8 + j];
    } else {
      int kk = k-256; int kg = kk>>3, j = kk&7;
      v = wb[o*32 + kg*8 + j];
    }
  }
  W[widx] = (__bf16)v;
}

__global__ __launch_bounds__(256,3)
void swin_kan_mfma(const float* __restrict__ x,
                   const float* __restrict__ pn_g, const float* __restrict__ pn_b,
                   const float* __restrict__ k1_bb, const float* __restrict__ k2_bb,
                   const float* __restrict__ k3_bb, const float* __restrict__ k4_bb,
                   const float* __restrict__ LNP,
                   const __bf16* __restrict__ Wbf,
                   float* __restrict__ out)
{
  __shared__ __attribute__((aligned(16))) float  yw[64][LDST];
  __shared__ __attribute__((aligned(16))) float  zA[64][LDST];
  __shared__ __attribute__((aligned(16))) float  LNPs[192];
  __shared__ __attribute__((aligned(16))) __bf16 W3s[9216];   // staged W3 (18432 B)
  __shared__ __attribute__((aligned(16))) s8v    TBL[TBL_N];  // basis LUT (15360 B)

  const int t   = threadIdx.x;
  const int bid = blockIdx.x;
  const int wid = (bid & 7)*512 + (bid >> 3);   // XCD-chunked swizzle (4096 % 8 == 0)
  const int b   = wid >> 10;
  const int h0  = ((wid >> 5) & 31) * 8;
  const int w0  = (wid & 31) * 8;
  const int wave = t >> 6;
  const int lane = t & 63;
  const int fn = lane & 15, kg = lane >> 4;

  float4 xv0, xv1;   // residual held in registers for phase 6

  // ---- phase 1: x load -> yw; stage LNP; async-stage W3; build basis LUT ----
  {
    int ch = t & 31, h = t >> 5;
    const float* src = x + (((size_t)(b*32 + ch)*256 + (h0+h))*256 + w0);
    xv0 = *(const float4*)(src);
    xv1 = *(const float4*)(src + 4);
    int p = h*8;
    yw[p+0][ch]=xv0.x; yw[p+1][ch]=xv0.y; yw[p+2][ch]=xv0.z; yw[p+3][ch]=xv0.w;
    yw[p+4][ch]=xv1.x; yw[p+5][ch]=xv1.y; yw[p+6][ch]=xv1.z; yw[p+7][ch]=xv1.w;
    if (t < 192) LNPs[t] = LNP[t];
    const char* gsrc  = (const char*)(Wbf + W3_OFF);
    char*       lbase = (char*)W3s;
    for (int c = wave; c < 18; c += 4){
      gl_lds16(gsrc + c*1024 + lane*16, lbase + c*1024);
    }
    // basis LUT: 960 entries, 4 per thread (visible after B1)
    #pragma unroll
    for (int i = 0; i < 4; i++){
      int e = t + i*256;
      if (e < TBL_N){
        float u = -4.0f + (float)e * (1.0f/64.0f);
        TBL[e] = b2s(basis8bf_(u));
      }
    }
  }
  WAVE_FENCE();   // phase 2 reads this wave's rows, other lanes' columns

  // ---- phase 2: in-place pre-LN on yw (wave-local rows) ----
  {
    int pos = t >> 2, part = t & 3;
    f4v a = *(const f4v*)&yw[pos][part*8];
    f4v c = *(const f4v*)&yw[pos][part*8+4];
    float s1 = a[0]+a[1]+a[2]+a[3]+c[0]+c[1]+c[2]+c[3];
    float s2 = a[0]*a[0]+a[1]*a[1]+a[2]*a[2]+a[3]*a[3]
             + c[0]*c[0]+c[1]*c[1]+c[2]*c[2]+c[3]*c[3];
    s1 += __shfl_xor(s1,1); s2 += __shfl_xor(s2,1);
    s1 += __shfl_xor(s1,2); s2 += __shfl_xor(s2,2);
    float mu  = s1*(1.0f/32.0f);
    float var = s2*(1.0f/32.0f) - mu*mu;
    float rs  = rsq_(var + 1e-5f);
    f4v g0 = *(const f4v*)&pn_g[part*8], g1 = *(const f4v*)&pn_g[part*8+4];
    f4v b0 = *(const f4v*)&pn_b[part*8], b1 = *(const f4v*)&pn_b[part*8+4];
    f4v o0, o1;
    #pragma unroll
    for (int j=0;j<4;j++){ o0[j] = (a[j]-mu)*rs*g0[j] + b0[j]; o1[j] = (c[j]-mu)*rs*g1[j] + b1[j]; }
    *(f4v*)&yw[pos][part*8]   = o0;
    *(f4v*)&yw[pos][part*8+4] = o1;
  }
  __syncthreads();   // B1: phase 3 reads all rows; drains W3 staging; LUT visible

  // ---- phase 3: k1 (waves 0,1) & k2 (waves 2,3); batched reads/stats; basis via LUT ----
  {
    const bool br2 = (wave >= 2);
    const __bf16* Wp  = Wbf + (br2 ? W2_OFF : 0);
    const float* bbp = br2 ? k2_bb : k1_bb;
    const int gb = br2 ? 32 : 0, b2b = gb + 16;
    s8v wfr[5];
    #pragma unroll
    for (int ks=0;ks<5;ks++) wfr[ks] = *(const s8v*)&Wp[fn*160 + ks*32 + kg*8];
    f4v bias = *(const f4v*)&bbp[kg*4];
    f4v G  = *(const f4v*)&LNPs[gb  + kg*4];
    f4v B2 = *(const f4v*)&LNPs[b2b + kg*4];

    f2v va[4], vb[4];
    #pragma unroll
    for (int mi=0; mi<4; mi++){
      const int ck = (wave & 1)*4 + mi;
      const int posA = br2 ? (ck*8 + 2*kg) : ((2*kg)*8 + ck);
      const int posB = posA + (br2 ? 1 : 8);
      va[mi] = *(const f2v*)&yw[posA][2*fn];
      vb[mi] = *(const f2v*)&yw[posB][2*fn];
    }
    float mu4[4], rs4[4];
    #pragma unroll
    for (int mi=0; mi<4; mi++){
      float s1 = va[mi][0]+va[mi][1]+vb[mi][0]+vb[mi][1];
      float s2 = va[mi][0]*va[mi][0]+va[mi][1]*va[mi][1]+vb[mi][0]*vb[mi][0]+vb[mi][1]*vb[mi][1];
      s1 += __shfl_xor(s1,16); s2 += __shfl_xor(s2,16);
      s1 += __shfl_xor(s1,32); s2 += __shfl_xor(s2,32);
      float mu = s1*(1.0f/16.0f);
      mu4[mi] = mu;
      rs4[mi] = rsq_(s2*(1.0f/16.0f) - mu*mu + 1e-5f);
    }
    f4v accs[4];
    #pragma unroll
    for (int mi=0; mi<4; mi++){
      float v[4] = { va[mi][0], va[mi][1], vb[mi][0], vb[mi][1] };
      b8v bb = {};
      #pragma unroll
      for (int j=0;j<4;j++) bb[j] = (__bf16)silu_(v[j]);
      f4v acc = bias;
      #pragma unroll
      for (int ks=0;ks<4;ks++){
        float pp = G[ks]*rs4[mi];
        float qq = __builtin_fmaf(-mu4[mi], pp, B2[ks]);
        float u  = __builtin_fmaf(v[ks], pp, qq);
        acc = __builtin_amdgcn_mfma_f32_16x16x32_bf16(wfr[ks], blut_(TBL, u), acc, 0,0,0);
      }
      acc = __builtin_amdgcn_mfma_f32_16x16x32_bf16(wfr[4], b2s(bb), acc, 0,0,0);
      accs[mi] = acc;
    }

    if (!br2){
      #pragma unroll
      for (int mi=0; mi<4; mi++){
        const int ck = (wave & 1)*4 + mi;
        *(f2v*)&zA[(2*kg+0)*8 + ck][2*fn] = f2v{accs[mi][0], accs[mi][1]};
        *(f2v*)&zA[(2*kg+1)*8 + ck][2*fn] = f2v{accs[mi][2], accs[mi][3]};
      }
    }
    __syncthreads();   // B2: k1 stores visible to k2 rmw
    if (br2){
      #pragma unroll
      for (int mi=0; mi<4; mi++){
        const int ck = (wave & 1)*4 + mi;
        f2v o0 = *(f2v*)&zA[ck*8 + 2*kg+0][2*fn];
        f2v o1 = *(f2v*)&zA[ck*8 + 2*kg+1][2*fn];
        o0[0] += accs[mi][0]; o0[1] += accs[mi][1];
        o1[0] += accs[mi][2]; o1[1] += accs[mi][3];
        *(f2v*)&zA[ck*8 + 2*kg+0][2*fn] = o0;
        *(f2v*)&zA[ck*8 + 2*kg+1][2*fn] = o1;
      }
    }
  }
  __syncthreads();   // B3: k2 writes visible to phase 4

  // ---- phase 4: k3 on yw -> zA += ; weights from LDS (W3s); basis via LUT ----
  {
    const int r = wave*16 + fn;
    f4v v0 = *(const f4v*)&yw[r][kg*8];
    f4v v1 = *(const f4v*)&yw[r][kg*8+4];
    float v[8] = { v0[0],v0[1],v0[2],v0[3], v1[0],v1[1],v1[2],v1[3] };
    b8v bb;
    #pragma unroll
    for (int ks=0;ks<8;ks++) bb[ks] = (__bf16)silu_(v[ks]);
    float s1=0.f, s2=0.f;
    #pragma unroll
    for (int ks=0;ks<8;ks++){ s1 += v[ks]; s2 += v[ks]*v[ks]; }
    s1 += __shfl_xor(s1,16); s2 += __shfl_xor(s2,16);
    s1 += __shfl_xor(s1,32); s2 += __shfl_xor(s2,32);
    float mu  = s1*(1.0f/32.0f);
    float var = s2*(1.0f/32.0f) - mu*mu;
    float rs  = rsq_(var + 1e-5f);

    f4v Ga = *(const f4v*)&LNPs[64 + kg*8], Gb = *(const f4v*)&LNPs[64 + kg*8 + 4];
    f4v Ba = *(const f4v*)&LNPs[96 + kg*8], Bb = *(const f4v*)&LNPs[96 + kg*8 + 4];
    float G8[8]  = { Ga[0],Ga[1],Ga[2],Ga[3], Gb[0],Gb[1],Gb[2],Gb[3] };
    float B8[8]  = { Ba[0],Ba[1],Ba[2],Ba[3], Bb[0],Bb[1],Bb[2],Bb[3] };

    f4v acc0 = *(const f4v*)&k3_bb[kg*4];
    f4v acc1 = *(const f4v*)&k3_bb[16 + kg*4];
    #pragma unroll
    for (int ks=0;ks<8;ks++){
      float pp = G8[ks]*rs;
      float qq = __builtin_fmaf(-mu, pp, B8[ks]);
      float u  = __builtin_fmaf(v[ks], pp, qq);
      s8v bf = blut_(TBL, u);
      s8v wa = *(const s8v*)&W3s[fn*288      + ks*32 + kg*8];
      s8v wb = *(const s8v*)&W3s[(16+fn)*288 + ks*32 + kg*8];
      acc0 = __builtin_amdgcn_mfma_f32_16x16x32_bf16(wa, bf, acc0, 0,0,0);
      acc1 = __builtin_amdgcn_mfma_f32_16x16x32_bf16(wb, bf, acc1, 0,0,0);
    }
    {
      s8v wa = *(const s8v*)&W3s[fn*288      + 256 + kg*8];
      s8v wb = *(const s8v*)&W3s[(16+fn)*288 + 256 + kg*8];
      acc0 = __builtin_amdgcn_mfma_f32_16x16x32_bf16(wa, b2s(bb), acc0, 0,0,0);
      acc1 = __builtin_amdgcn_mfma_f32_16x16x32_bf16(wb, b2s(bb), acc1, 0,0,0);
    }
    f4v za0 = *(const f4v*)&zA[r][kg*4];
    f4v za1 = *(const f4v*)&zA[r][16+kg*4];
    *(f4v*)&zA[r][kg*4]    = acc0 + za0;
    *(f4v*)&zA[r][16+kg*4] = acc1 + za1;
  }
  WAVE_FENCE();   // phase 5 reads same-wave rows, other lanes' columns

  // ---- phase 5: k4 on z=zA -> result into yw (wave-local); W4 via L1; basis via LUT ----
  {
    const int r = wave*16 + fn;
    f4v v0 = *(const f4v*)&zA[r][kg*8];
    f4v v1 = *(const f4v*)&zA[r][kg*8+4];
    float v[8] = { v0[0],v0[1],v0[2],v0[3], v1[0],v1[1],v1[2],v1[3] };
    float s1=0.f, s2=0.f;
    #pragma unroll
    for (int ks=0;ks<8;ks++){ s1 += v[ks]; s2 += v[ks]*v[ks]; }
    s1 += __shfl_xor(s1,16); s2 += __shfl_xor(s2,16);
    s1 += __shfl_xor(s1,32); s2 += __shfl_xor(s2,32);
    float mu  = s1*(1.0f/32.0f);
    float var = s2*(1.0f/32.0f) - mu*mu;
    float rs  = rsq_(var + 1e-5f);

    f4v Ga = *(const f4v*)&LNPs[128 + kg*8], Gb = *(const f4v*)&LNPs[128 + kg*8 + 4];
    f4v Ba = *(const f4v*)&LNPs[160 + kg*8], Bb = *(const f4v*)&LNPs[160 + kg*8 + 4];
    float G8[8]  = { Ga[0],Ga[1],Ga[2],Ga[3], Gb[0],Gb[1],Gb[2],Gb[3] };
    float B8[8]  = { Ba[0],Ba[1],Ba[2],Ba[3], Bb[0],Bb[1],Bb[2],Bb[3] };

    f4v acc0 = *(const f4v*)&k4_bb[kg*4];
    f4v acc1 = *(const f4v*)&k4_bb[16 + kg*4];
    b8v bb;
    #pragma unroll
    for (int ks=0;ks<8;ks++){
      float pp = G8[ks]*rs;
      float qq = __builtin_fmaf(-mu, pp, B8[ks]);
      float u  = __builtin_fmaf(v[ks], pp, qq);
      s8v bf = blut_(TBL, u);
      s8v wa = *(const s8v*)&Wbf[W4_OFF + fn*288      + ks*32 + kg*8];
      s8v wb = *(const s8v*)&Wbf[W4_OFF + (16+fn)*288 + ks*32 + kg*8];
      acc0 = __builtin_amdgcn_mfma_f32_16x16x32_bf16(wa, bf, acc0, 0,0,0);
      acc1 = __builtin_amdgcn_mfma_f32_16x16x32_bf16(wb, bf, acc1, 0,0,0);
      bb[ks] = (__bf16)silu_(v[ks]);
    }
    {
      s8v wa = *(const s8v*)&Wbf[W4_OFF + fn*288      + 256 + kg*8];
      s8v wb = *(const s8v*)&Wbf[W4_OFF + (16+fn)*288 + 256 + kg*8];
      acc0 = __builtin_amdgcn_mfma_f32_16x16x32_bf16(wa, b2s(bb), acc0, 0,0,0);
      acc1 = __builtin_amdgcn_mfma_f32_16x16x32_bf16(wb, b2s(bb), acc1, 0,0,0);
    }
    *(f4v*)&yw[r][kg*4]    = acc0;
    *(f4v*)&yw[r][16+kg*4] = acc1;
  }
  WAVE_FENCE();   // phase 6 reads same-wave rows, other lanes' columns

  // ---- phase 6: residual from registers + coalesced store ----
  {
    int ch = t & 31, h = t >> 5;
    const size_t base = (((size_t)(b*32 + ch)*256 + (h0+h))*256 + w0);
    int p = h*8;
    float4 v0 = { yw[p+0][ch]+xv0.x, yw[p+1][ch]+xv0.y, yw[p+2][ch]+xv0.z, yw[p+3][ch]+xv0.w };
    float4 v1 = { yw[p+4][ch]+xv1.x, yw[p+5][ch]+xv1.y, yw[p+6][ch]+xv1.z, yw[p+7][ch]+xv1.w };
    *(float4*)(out + base)     = v0;
    *(float4*)(out + base + 4) = v1;
  }
}

extern "C" void kernel_launch(void* const* d_in, const int* in_sizes, int n_in,
                              void* d_out, int out_size, void* d_ws, size_t ws_size,
                              hipStream_t stream) {
  const float* x      = (const float*)d_in[0];
  const float* pn_g   = (const float*)d_in[1];
  const float* pn_b   = (const float*)d_in[2];
  const float* k1_ln_g= (const float*)d_in[3];
  const float* k1_ln_b= (const float*)d_in[4];
  const float* k1_ws  = (const float*)d_in[5];
  const float* k1_wb  = (const float*)d_in[6];
  const float* k1_bb  = (const float*)d_in[7];
  const float* k2_ln_g= (const float*)d_in[8];
  const float* k2_ln_b= (const float*)d_in[9];
  const float* k2_ws  = (const float*)d_in[10];
  const float* k2_wb  = (const float*)d_in[11];
  const float* k2_bb  = (const float*)d_in[12];
  const float* k3_ln_g= (const float*)d_in[13];
  const float* k3_ln_b= (const float*)d_in[14];
  const float* k3_ws  = (const float*)d_in[15];
  const float* k3_wb  = (const float*)d_in[16];
  const float* k3_bb  = (const float*)d_in[17];
  const float* k4_ln_g= (const float*)d_in[18];
  const float* k4_ln_b= (const float*)d_in[19];
  const float* k4_ws  = (const float*)d_in[20];
  const float* k4_wb  = (const float*)d_in[21];
  const float* k4_bb  = (const float*)d_in[22];
  float* out = (float*)d_out;
  float*  LNP = (float*)d_ws;
  __bf16* Wbf = (__bf16*)((char*)d_ws + 768);

  hipLaunchKernelGGL(prep_w, dim3((PREP_TOTAL+255)/256), dim3(256), 0, stream,
                     k1_ws, k1_wb, k2_ws, k2_wb, k3_ws, k3_wb, k4_ws, k4_wb,
                     k1_ln_g, k1_ln_b, k2_ln_g, k2_ln_b,
                     k3_ln_g, k3_ln_b, k4_ln_g, k4_ln_b,
                     LNP, Wbf);

  hipLaunchKernelGGL(swin_kan_mfma, dim3(4096), dim3(256), 0, stream,
                     x, pn_g, pn_b,
                     k1_bb, k2_bb, k3_bb, k4_bb,
                     LNP, Wbf, out);
}